// Round 9
// baseline (466.235 us; speedup 1.0000x reference)
//
#include <hip/hip_runtime.h>
#include <hip/hip_bf16.h>

#define NN 100000      // nodes
#define NE 1000000     // edges
#define D  128         // hidden / input dim
#define NC 16          // classes

typedef short short8 __attribute__((ext_vector_type(8)));
typedef float f32x4  __attribute__((ext_vector_type(4)));

__device__ __forceinline__ float bf2f(ushort u) {
  union { unsigned int i; float f; } v; v.i = ((unsigned int)u) << 16; return v.f;
}
__device__ __forceinline__ ushort f2bf(float f) {
  union { float f; unsigned int i; } v; v.f = f;
  unsigned int x = v.i;
  return (ushort)((x + 0x7FFFu + ((x >> 16) & 1u)) >> 16);  // RNE
}

#define BSH 9
#define NBKT ((NN + 511) >> BSH)                 // 196
#define MS_NBLK 256
#define MS_EPB ((NE + MS_NBLK - 1) / MS_NBLK)    // 3907
#define CSR_CAP 8192

// ---- sniff dtypes + zero bucket histogram ----------------------------------
__global__ void sniff_k(const ushort* __restrict__ xr, const unsigned int* __restrict__ ei,
                        int* __restrict__ flags, int* __restrict__ bhist) {
  int t = threadIdx.x;
  if (t < NBKT) bhist[t] = 0;
  if (t != 0 || blockIdx.x != 0) return;
  int f32 = 0;
  for (int i = 0; i < 128; ++i) {
    unsigned int e = ((unsigned int)xr[i] >> 7) & 0xFFu;
    if (e < 97u || e > 157u) f32 = 1;
  }
  flags[0] = f32;
  unsigned int s = 0;
  for (int i = 1; i < 256; i += 2) s |= ei[i];   // int64 < 2^31 => hi words all 0
  flags[1] = (s == 0) ? 1 : 0;
}

// ---- indices + fused dst bucket histogram, grid-stride 256 blocks ----------
__global__ __launch_bounds__(256) void convert_idx_k(
    const int* __restrict__ ei, const int* __restrict__ flags,
    int* __restrict__ idx, int* __restrict__ bhist) {
  __shared__ int h[NBKT];
  for (int t = threadIdx.x; t < NBKT; t += 256) h[t] = 0;
  __syncthreads();
  const int stride = 256 * 256;
  const int i64 = flags[1];
  for (int i = blockIdx.x * 256 + threadIdx.x; i < 2 * NE; i += stride) {
    int v = i64 ? ei[2 * i] : ei[i];   // int64: take low word
    v = v < 0 ? 0 : (v >= NN ? NN - 1 : v);
    idx[i] = v;
    if (i >= NE) atomicAdd(&h[v >> BSH], 1);   // dst half feeds histogram
  }
  __syncthreads();
  for (int t = threadIdx.x; t < NBKT; t += 256) if (h[t]) atomicAdd(&bhist[t], h[t]);
}

// ---- convert x to canonical bf16 -------------------------------------------
__global__ void convert_x_k(const void* __restrict__ xin, const int* __restrict__ flags,
                            ushort* __restrict__ xb) {
  int i = blockIdx.x * blockDim.x + threadIdx.x;
  const int n4 = NN * D / 4;
  if (i >= n4) return;
  ushort4 o;
  if (flags[0]) {
    float4 v = ((const float4*)xin)[i];
    o.x = f2bf(v.x); o.y = f2bf(v.y); o.z = f2bf(v.z); o.w = f2bf(v.w);
  } else {
    o = ((const ushort4*)xin)[i];
  }
  ((ushort4*)xb)[i] = o;
}

// ---- convert all weights/biases to canonical bf16 block --------------------
struct WPtrs { const void* p[10]; };
#define WTOT 102800
__global__ void convert_w_k(WPtrs w, const int* __restrict__ flags, ushort* __restrict__ wb) {
  const int off[10] = {0, 16384, 32768, 49152, 65536, 98304, 102400, 102528, 102656, 102784};
  int i = blockIdx.x * blockDim.x + threadIdx.x;
  if (i >= WTOT) return;
  int seg = 0;
  #pragma unroll
  for (int s2 = 1; s2 < 10; ++s2) if (i >= off[s2]) seg = s2;
  int j = i - off[seg];
  wb[i] = flags[0] ? f2bf(((const float*)w.p[seg])[j]) : ((const ushort*)w.p[seg])[j];
}

// ============================================================================
// CSR build, two-level multisplit
// ============================================================================
__global__ __launch_bounds__(256) void scanb_k(const int* __restrict__ bhist,
                                               int* __restrict__ bstart,
                                               int* __restrict__ bcur) {
  __shared__ int tmp[256];
  const int t = threadIdx.x;
  int v = (t < NBKT) ? bhist[t] : 0;
  tmp[t] = v;
  __syncthreads();
  for (int s = 1; s < 256; s <<= 1) {
    int u = (t >= s) ? tmp[t - s] : 0;
    __syncthreads();
    tmp[t] += u;
    __syncthreads();
  }
  if (t < NBKT) {
    int ex = tmp[t] - v;
    bstart[t] = ex;
    bcur[t] = ex;
  }
  if (t == NBKT - 1) bstart[NBKT] = tmp[t];
}

__global__ __launch_bounds__(512) void msplit_k(const int* __restrict__ src,
                                                const int* __restrict__ dst,
                                                int* __restrict__ bcur,
                                                int2* __restrict__ ebuf) {
  __shared__ int2 ep[MS_EPB];        // ~31.3 KiB
  __shared__ int hist[NBKT];
  __shared__ int gbase[NBKT];
  const int e0 = blockIdx.x * MS_EPB;
  int n = NE - e0; if (n > MS_EPB) n = MS_EPB;
  for (int t = threadIdx.x; t < NBKT; t += 512) hist[t] = 0;
  __syncthreads();
  for (int t = threadIdx.x; t < n; t += 512) {
    int s = src[e0 + t], d = dst[e0 + t];
    ep[t] = make_int2(s, d);
    atomicAdd(&hist[d >> BSH], 1);
  }
  __syncthreads();
  for (int t = threadIdx.x; t < NBKT; t += 512) {
    gbase[t] = atomicAdd(&bcur[t], hist[t]);   // one chunk per (block,bucket)
    hist[t] = 0;                               // reuse as local cursor
  }
  __syncthreads();
  for (int t = threadIdx.x; t < n; t += 512) {
    int2 p = ep[t];
    int b = p.y >> BSH;
    int loc = atomicAdd(&hist[b], 1);
    ebuf[gbase[b] + loc] = p;                  // contiguous within chunk
  }
}

// nbr[] stores src*128 (pre-scaled element offset) — agg_k saves a mul/widen
__global__ __launch_bounds__(512) void csr_k(const int2* __restrict__ ebuf,
                                             const int* __restrict__ bstart,
                                             int* __restrict__ off,
                                             int* __restrict__ nbr) {
  __shared__ int cnt_s[512];
  __shared__ int ofs_s[512];
  __shared__ int lnbr[CSR_CAP];      // 32 KiB staging
  const int b = blockIdx.x;
  const int n0 = b << BSH;
  int nn = NN - n0; if (nn > 512) nn = 512;
  const int e0 = bstart[b], e1 = bstart[b + 1];
  const int n = e1 - e0;
  const int t = threadIdx.x;
  cnt_s[t] = 0;
  __syncthreads();
  for (int i = t; i < n; i += 512)
    atomicAdd(&cnt_s[ebuf[e0 + i].y - n0], 1);
  __syncthreads();
  int v = cnt_s[t];
  ofs_s[t] = v;
  __syncthreads();
  for (int s = 1; s < 512; s <<= 1) {          // inclusive Hillis-Steele
    int u = (t >= s) ? ofs_s[t - s] : 0;
    __syncthreads();
    ofs_s[t] += u;
    __syncthreads();
  }
  const int excl = ofs_s[t] - v;
  if (t < nn) off[n0 + t] = e0 + excl;
  if (b == gridDim.x - 1 && t == 0) off[NN] = e1;   // == NE
  cnt_s[t] = excl;                 // becomes scatter cursor
  __syncthreads();
  if (n <= CSR_CAP) {
    for (int i = t; i < n; i += 512) {
      int2 p = ebuf[e0 + i];
      int loc = atomicAdd(&cnt_s[p.y - n0], 1);
      lnbr[loc] = p.x << 7;        // pre-scaled by D
    }
    __syncthreads();
    for (int i = t; i < n; i += 512) nbr[e0 + i] = lnbr[i];   // coalesced
  } else {                         // safety fallback (never expected)
    for (int i = t; i < n; i += 512) {
      int2 p = ebuf[e0 + i];
      int loc = atomicAdd(&cnt_s[p.y - n0], 1);
      nbr[e0 + loc] = p.x << 7;
    }
  }
}

// ---- segmented mean: one wave per node; 4 edge-groups x 16 lanes x 16B -----
// nbr[] holds pre-scaled src*D element offsets.
__global__ __launch_bounds__(256) void agg_k(
    const ushort* __restrict__ X, const int* __restrict__ nbr,
    const int* __restrict__ off, ushort* __restrict__ mean) {
  const int wave = threadIdx.x >> 6, lane = threadIdx.x & 63;
  const int node = blockIdx.x * 4 + wave;
  if (node >= NN) return;
  const int j0 = off[node], j1 = off[node + 1];
  const int g = lane >> 4, l15 = lane & 15;
  float a[8];
  #pragma unroll
  for (int k = 0; k < 8; ++k) a[k] = 0.f;
  int j = j0 + g;
  for (; j + 4 < j1; j += 8) {     // 2 edges per group in flight
    int s0 = nbr[j], s1 = nbr[j + 4];
    uint4 v0 = *(const uint4*)(X + (size_t)(unsigned)s0 + l15 * 8);
    uint4 v1 = *(const uint4*)(X + (size_t)(unsigned)s1 + l15 * 8);
    unsigned int w0[4] = {v0.x, v0.y, v0.z, v0.w};
    unsigned int w1[4] = {v1.x, v1.y, v1.z, v1.w};
    #pragma unroll
    for (int k = 0; k < 4; ++k) {
      union { unsigned int u; float f; } lo0, hi0, lo1, hi1;
      lo0.u = w0[k] << 16; hi0.u = w0[k] & 0xffff0000u;
      lo1.u = w1[k] << 16; hi1.u = w1[k] & 0xffff0000u;
      a[2 * k]     += lo0.f + lo1.f;
      a[2 * k + 1] += hi0.f + hi1.f;
    }
  }
  if (j < j1) {
    uint4 v0 = *(const uint4*)(X + (size_t)(unsigned)nbr[j] + l15 * 8);
    unsigned int w0[4] = {v0.x, v0.y, v0.z, v0.w};
    #pragma unroll
    for (int k = 0; k < 4; ++k) {
      union { unsigned int u; float f; } lo0, hi0;
      lo0.u = w0[k] << 16; hi0.u = w0[k] & 0xffff0000u;
      a[2 * k]     += lo0.f;
      a[2 * k + 1] += hi0.f;
    }
  }
  #pragma unroll
  for (int k = 0; k < 8; ++k) {    // reduce the 4 edge-groups
    a[k] += __shfl_xor(a[k], 16, 64);
    a[k] += __shfl_xor(a[k], 32, 64);
  }
  if (g == 0) {
    int deg = j1 - j0;
    float inv = 1.f / (float)(deg > 1 ? deg : 1);
    uint4 o;
    o.x = (unsigned int)f2bf(a[0] * inv) | ((unsigned int)f2bf(a[1] * inv) << 16);
    o.y = (unsigned int)f2bf(a[2] * inv) | ((unsigned int)f2bf(a[3] * inv) << 16);
    o.z = (unsigned int)f2bf(a[4] * inv) | ((unsigned int)f2bf(a[5] * inv) << 16);
    o.w = (unsigned int)f2bf(a[6] * inv) | ((unsigned int)f2bf(a[7] * inv) << 16);
    *(uint4*)(mean + (size_t)node * D + l15 * 8) = o;
  }
}

// ============================================================================
// Fused SAGE layer: Y = relu([X, relu(mean@Wl^T + X@Wr^T + bl)] @ Wc^T + bc)
// h via wave-private LDS (round-8 verified). ROUND-9: software-pipelined W
// staging (T14 issue-early/write-late): stage s+1's 4 uint4 global loads are
// issued into registers BEFORE stage s's MFMA cluster, committed to LDS after
// the next barrier — L2 latency hides under 16 MFMA + ds_reads. Plus
// __launch_bounds__(256,3): est. peak ~160 VGPR fits 168 → 3 blocks/CU
// (LDS 49KB allows 3). If spilled, WRITE_SIZE will show it.
// ============================================================================
#define ISSUE_W(Wp, ldwv, HALF)                                                \
  _Pragma("unroll")                                                            \
  for (int it = 0; it < 4; ++it) {                                             \
    int combo = it * 4 + wave;                                                 \
    int cc = combo >> 2, kk = combo & 3;                                       \
    pf[it] = *(const uint4*)((Wp) + (size_t)(((HALF) * 4 + cc) * 16 + l15) * (ldwv) + kk * 32 + q * 8); \
  }

#define COMMIT_W()                                                             \
  __syncthreads();                                                             \
  _Pragma("unroll")                                                            \
  for (int it = 0; it < 4; ++it) {                                             \
    int combo = it * 4 + wave;                                                 \
    *(uint4*)(&wlds[(combo * 64 + lane) * 8]) = pf[it];                        \
  }                                                                            \
  __syncthreads();

#define MFMA_HALF(bfr, HALF)                                                   \
  _Pragma("unroll")                                                            \
  for (int ks = 0; ks < 4; ++ks)                                               \
    _Pragma("unroll")                                                          \
    for (int cl = 0; cl < 4; ++cl) {                                           \
      short8 bf = *(const short8*)(&wlds[((cl * 4 + ks) * 64 + lane) * 8]);    \
      acc[0][(HALF) * 4 + cl] =                                                \
          __builtin_amdgcn_mfma_f32_16x16x32_bf16(bf, (bfr)[0][ks], acc[0][(HALF) * 4 + cl], 0, 0, 0); \
      acc[1][(HALF) * 4 + cl] =                                                \
          __builtin_amdgcn_mfma_f32_16x16x32_bf16(bf, (bfr)[1][ks], acc[1][(HALF) * 4 + cl], 0, 0, 0); \
    }

#define MFMA_HHALF(HALF)                                                       \
  _Pragma("unroll")                                                            \
  for (int ks = 0; ks < 4; ++ks) {                                             \
    short8 h0 = *(const short8*)(&hlds[hb0 + ks * 32 + q * 8]);                \
    short8 h1 = *(const short8*)(&hlds[hb1 + ks * 32 + q * 8]);                \
    _Pragma("unroll")                                                          \
    for (int cl = 0; cl < 4; ++cl) {                                           \
      short8 bf = *(const short8*)(&wlds[((cl * 4 + ks) * 64 + lane) * 8]);    \
      acc[0][(HALF) * 4 + cl] =                                                \
          __builtin_amdgcn_mfma_f32_16x16x32_bf16(bf, h0, acc[0][(HALF) * 4 + cl], 0, 0, 0); \
      acc[1][(HALF) * 4 + cl] =                                                \
          __builtin_amdgcn_mfma_f32_16x16x32_bf16(bf, h1, acc[1][(HALF) * 4 + cl], 0, 0, 0); \
    }                                                                          \
  }

#define HLDW 132   // ushorts per h row (264B): b128 reads 2 lanes/bank (free)

__global__ __launch_bounds__(256, 3) void fused_layer_k(
    const ushort* __restrict__ MEAN, const ushort* __restrict__ X,
    const ushort* __restrict__ Wl, const ushort* __restrict__ Wr,
    const ushort* __restrict__ Wc,   // [128][256] row-major
    const ushort* __restrict__ bl, const ushort* __restrict__ bc,
    ushort* __restrict__ Y, int nrows)
{
  __shared__ ushort wlds[16 * 64 * 8];     // 16 KiB W half-stage
  __shared__ ushort hlds[128 * HLDW];      // 33 KiB h (wave-private 32-row slices)
  const int tid = threadIdx.x;
  const int wave = tid >> 6, lane = tid & 63;
  const int l15 = lane & 15, q = lane >> 4;
  const int nb = blockIdx.x * 128 + wave * 32;   // this wave's 32 node rows

  int r0 = nb + l15;      if (r0 > nrows - 1) r0 = nrows - 1;  // clamp (stores guarded)
  int r1 = nb + 16 + l15; if (r1 > nrows - 1) r1 = nrows - 1;

  // node B-fragments (lane16 = node, q*8 contiguous k)
  short8 am[2][4], ax[2][4];
  #pragma unroll
  for (int ks = 0; ks < 4; ++ks) {
    am[0][ks] = *(const short8*)(MEAN + (size_t)r0 * D + ks * 32 + q * 8);
    am[1][ks] = *(const short8*)(MEAN + (size_t)r1 * D + ks * 32 + q * 8);
    ax[0][ks] = *(const short8*)(X    + (size_t)r0 * D + ks * 32 + q * 8);
    ax[1][ks] = *(const short8*)(X    + (size_t)r1 * D + ks * 32 + q * 8);
  }

  f32x4 acc[2][8];
  #pragma unroll
  for (int rt = 0; rt < 2; ++rt)
    #pragma unroll
    for (int c = 0; c < 8; ++c) acc[rt][c] = (f32x4){0.f, 0.f, 0.f, 0.f};

  uint4 pf[4];   // W prefetch registers (one 16KB half-stage in flight)

  // ---- GEMM1: h = relu(mean@Wl^T + X@Wr^T + bl), pipelined -----------------
  ISSUE_W(Wl, D, 0);
  COMMIT_W();  ISSUE_W(Wl, D, 1);      MFMA_HALF(am, 0);
  COMMIT_W();  ISSUE_W(Wr, D, 0);      MFMA_HALF(am, 1);
  COMMIT_W();  ISSUE_W(Wr, D, 1);      MFMA_HALF(ax, 0);
  COMMIT_W();  ISSUE_W(Wc, 2 * D, 0);  MFMA_HALF(ax, 1);

  // epilogue1: bias+relu, write h packs to wave-private LDS (no barrier:
  // this wave alone writes/reads rows nb..nb+31); Wc loads already in flight
  #pragma unroll
  for (int c = 0; c < 8; ++c) {
    ushort4 bv = *(const ushort4*)(bl + c * 16 + q * 4);
    #pragma unroll
    for (int rt = 0; rt < 2; ++rt) {
      float v0 = acc[rt][c][0] + bf2f(bv.x); v0 = v0 > 0.f ? v0 : 0.f;
      float v1 = acc[rt][c][1] + bf2f(bv.y); v1 = v1 > 0.f ? v1 : 0.f;
      float v2 = acc[rt][c][2] + bf2f(bv.z); v2 = v2 > 0.f ? v2 : 0.f;
      float v3 = acc[rt][c][3] + bf2f(bv.w); v3 = v3 > 0.f ? v3 : 0.f;
      uint2 o;
      o.x = (unsigned int)f2bf(v0) | ((unsigned int)f2bf(v1) << 16);
      o.y = (unsigned int)f2bf(v2) | ((unsigned int)f2bf(v3) << 16);
      int nl = wave * 32 + rt * 16 + l15;          // local row this lane produced
      *(uint2*)(&hlds[nl * HLDW + c * 16 + q * 4]) = o;
    }
  }
  #pragma unroll
  for (int rt = 0; rt < 2; ++rt)
    #pragma unroll
    for (int c = 0; c < 8; ++c) acc[rt][c] = (f32x4){0.f, 0.f, 0.f, 0.f};

  const int hb0 = (wave * 32 + l15) * HLDW;        // h B-frag row for rt=0
  const int hb1 = (wave * 32 + 16 + l15) * HLDW;   // h B-frag row for rt=1

  // ---- GEMM2: Y = relu(X@Wc[:, :128]^T + h@Wc[:, 128:]^T + bc), pipelined --
  COMMIT_W();  ISSUE_W(Wc, 2 * D, 1);      MFMA_HALF(ax, 0);
  COMMIT_W();  ISSUE_W(Wc + D, 2 * D, 0);  MFMA_HALF(ax, 1);
  COMMIT_W();  ISSUE_W(Wc + D, 2 * D, 1);  MFMA_HHALF(0);
  COMMIT_W();                              MFMA_HHALF(1);

  // epilogue2: bias+relu, packed 8B stores (node row, 4 consecutive cols)
  #pragma unroll
  for (int c = 0; c < 8; ++c) {
    ushort4 bv = *(const ushort4*)(bc + c * 16 + q * 4);
    #pragma unroll
    for (int rt = 0; rt < 2; ++rt) {
      int node = nb + rt * 16 + l15;
      if (node < nrows) {
        float v0 = acc[rt][c][0] + bf2f(bv.x); v0 = v0 > 0.f ? v0 : 0.f;
        float v1 = acc[rt][c][1] + bf2f(bv.y); v1 = v1 > 0.f ? v1 : 0.f;
        float v2 = acc[rt][c][2] + bf2f(bv.z); v2 = v2 > 0.f ? v2 : 0.f;
        float v3 = acc[rt][c][3] + bf2f(bv.w); v3 = v3 > 0.f ? v3 : 0.f;
        uint2 o;
        o.x = (unsigned int)f2bf(v0) | ((unsigned int)f2bf(v1) << 16);
        o.y = (unsigned int)f2bf(v2) | ((unsigned int)f2bf(v3) << 16);
        *(uint2*)(Y + (size_t)node * D + c * 16 + q * 4) = o;
      }
    }
  }
}

// ---- P[node, 0:16] = x2[node] @ Wo[:, 0:128]^T ; P[node,16:32] = @ Wo[:,128:]^T
__global__ __launch_bounds__(256) void gemm_po(
    const ushort* __restrict__ X2, const ushort* __restrict__ Wo, float* __restrict__ P)
{
  const int tid = threadIdx.x, wave = tid >> 6, lane = tid & 63;
  const int l15 = lane & 15, q = lane >> 4;
  const int m0 = blockIdx.x * 64 + wave * 16;
  int row = m0 + l15; if (row > NN - 1) row = NN - 1;
  f32x4 acc[2] = {(f32x4){0.f,0.f,0.f,0.f}, (f32x4){0.f,0.f,0.f,0.f}};
  #pragma unroll
  for (int ks = 0; ks < 4; ++ks) {
    short8 af = *(const short8*)(X2 + (size_t)row * D + ks * 32 + q * 8);
    #pragma unroll
    for (int c = 0; c < 2; ++c) {
      short8 bf = *(const short8*)(Wo + (size_t)l15 * 256 + c * 128 + ks * 32 + q * 8);
      acc[c] = __builtin_amdgcn_mfma_f32_16x16x32_bf16(af, bf, acc[c], 0, 0, 0);
    }
  }
  #pragma unroll
  for (int c = 0; c < 2; ++c)
    #pragma unroll
    for (int r = 0; r < 4; ++r) {
      int orow = m0 + q * 4 + r;
      if (orow < NN) P[(size_t)orow * 32 + c * 16 + l15] = acc[c][r];
    }
}

// ---- out[e,c] = P[src[e]][c] + P[dst[e]][16+c] + bo[c] ---------------------
__global__ __launch_bounds__(256) void edge_sum_k(
    const float* __restrict__ P, const int* __restrict__ src, const int* __restrict__ dst,
    const ushort* __restrict__ bo, const int* __restrict__ flags,
    void* __restrict__ outv, int E)
{
  int gid = blockIdx.x * blockDim.x + threadIdx.x;
  if (gid >= E * 4) return;
  int e = gid >> 2, cq = (gid & 3) * 4;
  int s = src[e], d = dst[e];
  float4 a = *(const float4*)(P + (size_t)s * 32 + cq);
  float4 b = *(const float4*)(P + (size_t)d * 32 + 16 + cq);
  float4 o;
  o.x = a.x + b.x + bf2f(bo[cq + 0]);
  o.y = a.y + b.y + bf2f(bo[cq + 1]);
  o.z = a.z + b.z + bf2f(bo[cq + 2]);
  o.w = a.w + b.w + bf2f(bo[cq + 3]);
  if (flags[0]) {
    ((float4*)outv)[gid] = o;
  } else {
    ushort4 u;
    u.x = f2bf(o.x); u.y = f2bf(o.y); u.z = f2bf(o.z); u.w = f2bf(o.w);
    ((ushort4*)outv)[gid] = u;
  }
}

extern "C" void kernel_launch(void* const* d_in, const int* in_sizes, int n_in,
                              void* d_out, int out_size, void* d_ws, size_t ws_size,
                              hipStream_t stream) {
  const void* x_in = d_in[0];
  const int*  ei   = (const int*)d_in[1];

  // workspace layout (bytes): total ~64.6 MB
  char* ws = (char*)d_ws;
  int*    idx   = (int*)(ws + 0);              //  8,000,000 (src | dst)
  int*    bhist = (int*)(ws + 8000000);        //        784 (NBKT)
  int*    flags = (int*)(ws + 8400000);        //        256
  ushort* wb    = (ushort*)(ws + 8400256);     //    205,600
  int*    off   = (int*)(ws + 8605856);        //    400,004
  int*    bstart= (int*)(ws + 9005872);        //        788 (NBKT+1)
  int*    nbr   = (int*)(ws + 9405872);        //  4,000,000
  int*    bcur  = (int*)(ws + 13405872);       //        784
  ushort* buf1  = (ushort*)(ws + 13407440);    // 25,600,000 (ebuf -> x1 -> P)
  ushort* buf2  = (ushort*)(ws + 39007440);    // 25,600,000 (xb / x2)
  ushort* dscr  = (ushort*)d_out;              // d_out scratch: meanL0 / meanL1
  float*  P     = (float*)buf1;                // alias: buf1 dead after fused L1
  int2*   ebuf  = (int2*)buf1;                 // alias: dead before fused L0

  int* src = idx;
  int* dst = idx + NE;

  ushort* Wl0 = wb + 0,      *Wr0 = wb + 16384, *Wl1 = wb + 32768, *Wr1 = wb + 49152;
  ushort* Wc  = wb + 65536,  *Wo  = wb + 98304;
  ushort* bl0 = wb + 102400, *bl1 = wb + 102528, *bc = wb + 102656, *bo = wb + 102784;

  WPtrs w;
  w.p[0] = d_in[2];  w.p[1] = d_in[4];  w.p[2] = d_in[5];  w.p[3] = d_in[7];
  w.p[4] = d_in[8];  w.p[5] = d_in[10]; w.p[6] = d_in[3];  w.p[7] = d_in[6];
  w.p[8] = d_in[9];  w.p[9] = d_in[11];

  const int gblocks = (NN + 127) / 128;        // 782
  const int n4 = NN * D / 4;
  const int agrid = (NN + 3) / 4;              // 25,000 (4 nodes/block)

  sniff_k<<<1, 256, 0, stream>>>((const ushort*)x_in, (const unsigned int*)ei, flags, bhist);
  convert_idx_k<<<256, 256, 0, stream>>>(ei, flags, idx, bhist);
  convert_x_k<<<(n4 + 255) / 256, 256, 0, stream>>>(x_in, flags, buf2);
  convert_w_k<<<(WTOT + 255) / 256, 256, 0, stream>>>(w, flags, wb);

  // ---- build CSR via two-level multisplit ----------------------------------
  scanb_k<<<1, 256, 0, stream>>>(bhist, bstart, bcur);
  msplit_k<<<MS_NBLK, 512, 0, stream>>>(src, dst, bcur, ebuf);
  csr_k<<<NBKT, 512, 0, stream>>>(ebuf, bstart, off, nbr);

  // ---- layer 0: x=buf2 -> mean=dscr -> x1=buf1 (h stays on-chip) -----------
  agg_k<<<agrid, 256, 0, stream>>>(buf2, nbr, off, dscr);
  fused_layer_k<<<gblocks, 256, 0, stream>>>(dscr, buf2, Wl0, Wr0, Wc, bl0, bc, buf1, NN);

  // ---- layer 1: x1=buf1 -> mean=dscr -> x2=buf2 ----------------------------
  agg_k<<<agrid, 256, 0, stream>>>(buf1, nbr, off, dscr);
  fused_layer_k<<<gblocks, 256, 0, stream>>>(dscr, buf1, Wl1, Wr1, Wc, bl1, bc, buf2, NN);

  // ---- edge classifier: factored P-GEMM + gather-sum -----------------------
  gemm_po<<<(NN + 63) / 64, 256, 0, stream>>>(buf2, Wo, P);
  edge_sum_k<<<(4 * NE + 255) / 256, 256, 0, stream>>>(P, src, dst, bo, flags, d_out, NE);
}

// Round 10
// 417.186 us; speedup vs baseline: 1.1176x; 1.1176x over previous
//
#include <hip/hip_runtime.h>
#include <hip/hip_bf16.h>

#define NN 100000      // nodes
#define NE 1000000     // edges
#define D  128         // hidden / input dim
#define NC 16          // classes

typedef short short8 __attribute__((ext_vector_type(8)));
typedef float f32x4  __attribute__((ext_vector_type(4)));

__device__ __forceinline__ float bf2f(ushort u) {
  union { unsigned int i; float f; } v; v.i = ((unsigned int)u) << 16; return v.f;
}
__device__ __forceinline__ ushort f2bf(float f) {
  union { float f; unsigned int i; } v; v.f = f;
  unsigned int x = v.i;
  return (ushort)((x + 0x7FFFu + ((x >> 16) & 1u)) >> 16);  // RNE
}

#define BSH 9
#define NBKT ((NN + 511) >> BSH)                 // 196
#define MS_NBLK 256
#define MS_EPB ((NE + MS_NBLK - 1) / MS_NBLK)    // 3907
#define CSR_CAP 8192

// ---- sniff dtypes + zero bucket histogram ----------------------------------
__global__ void sniff_k(const ushort* __restrict__ xr, const unsigned int* __restrict__ ei,
                        int* __restrict__ flags, int* __restrict__ bhist) {
  int t = threadIdx.x;
  if (t < NBKT) bhist[t] = 0;
  if (t != 0 || blockIdx.x != 0) return;
  int f32 = 0;
  for (int i = 0; i < 128; ++i) {
    unsigned int e = ((unsigned int)xr[i] >> 7) & 0xFFu;
    if (e < 97u || e > 157u) f32 = 1;
  }
  flags[0] = f32;
  unsigned int s = 0;
  for (int i = 1; i < 256; i += 2) s |= ei[i];   // int64 < 2^31 => hi words all 0
  flags[1] = (s == 0) ? 1 : 0;
}

// ---- indices + fused dst bucket histogram, grid-stride 256 blocks ----------
__global__ __launch_bounds__(256) void convert_idx_k(
    const int* __restrict__ ei, const int* __restrict__ flags,
    int* __restrict__ idx, int* __restrict__ bhist) {
  __shared__ int h[NBKT];
  for (int t = threadIdx.x; t < NBKT; t += 256) h[t] = 0;
  __syncthreads();
  const int stride = 256 * 256;
  const int i64 = flags[1];
  for (int i = blockIdx.x * 256 + threadIdx.x; i < 2 * NE; i += stride) {
    int v = i64 ? ei[2 * i] : ei[i];   // int64: take low word
    v = v < 0 ? 0 : (v >= NN ? NN - 1 : v);
    idx[i] = v;
    if (i >= NE) atomicAdd(&h[v >> BSH], 1);   // dst half feeds histogram
  }
  __syncthreads();
  for (int t = threadIdx.x; t < NBKT; t += 256) if (h[t]) atomicAdd(&bhist[t], h[t]);
}

// ---- convert x to canonical bf16 -------------------------------------------
__global__ void convert_x_k(const void* __restrict__ xin, const int* __restrict__ flags,
                            ushort* __restrict__ xb) {
  int i = blockIdx.x * blockDim.x + threadIdx.x;
  const int n4 = NN * D / 4;
  if (i >= n4) return;
  ushort4 o;
  if (flags[0]) {
    float4 v = ((const float4*)xin)[i];
    o.x = f2bf(v.x); o.y = f2bf(v.y); o.z = f2bf(v.z); o.w = f2bf(v.w);
  } else {
    o = ((const ushort4*)xin)[i];
  }
  ((ushort4*)xb)[i] = o;
}

// ---- bucket scan (block 0) + weight conversion (blocks 1..) ----------------
struct WPtrs { const void* p[10]; };
#define WTOT 102800
__global__ __launch_bounds__(256) void scan_convw_k(
    const int* __restrict__ bhist, int* __restrict__ bstart, int* __restrict__ bcur,
    WPtrs w, const int* __restrict__ flags, ushort* __restrict__ wb) {
  if (blockIdx.x == 0) {
    __shared__ int tmp[256];
    const int t = threadIdx.x;
    int v = (t < NBKT) ? bhist[t] : 0;
    tmp[t] = v;
    __syncthreads();
    for (int s = 1; s < 256; s <<= 1) {
      int u = (t >= s) ? tmp[t - s] : 0;
      __syncthreads();
      tmp[t] += u;
      __syncthreads();
    }
    if (t < NBKT) {
      int ex = tmp[t] - v;
      bstart[t] = ex;
      bcur[t] = ex;
    }
    if (t == NBKT - 1) bstart[NBKT] = tmp[t];
  } else {
    const int off[10] = {0, 16384, 32768, 49152, 65536, 98304, 102400, 102528, 102656, 102784};
    int i = (blockIdx.x - 1) * 256 + threadIdx.x;
    if (i >= WTOT) return;
    int seg = 0;
    #pragma unroll
    for (int s2 = 1; s2 < 10; ++s2) if (i >= off[s2]) seg = s2;
    int j = i - off[seg];
    wb[i] = flags[0] ? f2bf(((const float*)w.p[seg])[j]) : ((const ushort*)w.p[seg])[j];
  }
}

__global__ __launch_bounds__(512) void msplit_k(const int* __restrict__ src,
                                                const int* __restrict__ dst,
                                                int* __restrict__ bcur,
                                                int2* __restrict__ ebuf) {
  __shared__ int2 ep[MS_EPB];        // ~31.3 KiB
  __shared__ int hist[NBKT];
  __shared__ int gbase[NBKT];
  const int e0 = blockIdx.x * MS_EPB;
  int n = NE - e0; if (n > MS_EPB) n = MS_EPB;
  for (int t = threadIdx.x; t < NBKT; t += 512) hist[t] = 0;
  __syncthreads();
  for (int t = threadIdx.x; t < n; t += 512) {
    int s = src[e0 + t], d = dst[e0 + t];
    ep[t] = make_int2(s, d);
    atomicAdd(&hist[d >> BSH], 1);
  }
  __syncthreads();
  for (int t = threadIdx.x; t < NBKT; t += 512) {
    gbase[t] = atomicAdd(&bcur[t], hist[t]);   // one chunk per (block,bucket)
    hist[t] = 0;                               // reuse as local cursor
  }
  __syncthreads();
  for (int t = threadIdx.x; t < n; t += 512) {
    int2 p = ep[t];
    int b = p.y >> BSH;
    int loc = atomicAdd(&hist[b], 1);
    ebuf[gbase[b] + loc] = p;                  // contiguous within chunk
  }
}

// nbr[] stores src*128 (pre-scaled element offset) — agg_k saves a mul/widen
__global__ __launch_bounds__(512) void csr_k(const int2* __restrict__ ebuf,
                                             const int* __restrict__ bstart,
                                             int* __restrict__ off,
                                             int* __restrict__ nbr) {
  __shared__ int cnt_s[512];
  __shared__ int ofs_s[512];
  __shared__ int lnbr[CSR_CAP];      // 32 KiB staging
  const int b = blockIdx.x;
  const int n0 = b << BSH;
  int nn = NN - n0; if (nn > 512) nn = 512;
  const int e0 = bstart[b], e1 = bstart[b + 1];
  const int n = e1 - e0;
  const int t = threadIdx.x;
  cnt_s[t] = 0;
  __syncthreads();
  for (int i = t; i < n; i += 512)
    atomicAdd(&cnt_s[ebuf[e0 + i].y - n0], 1);
  __syncthreads();
  int v = cnt_s[t];
  ofs_s[t] = v;
  __syncthreads();
  for (int s = 1; s < 512; s <<= 1) {          // inclusive Hillis-Steele
    int u = (t >= s) ? ofs_s[t - s] : 0;
    __syncthreads();
    ofs_s[t] += u;
    __syncthreads();
  }
  const int excl = ofs_s[t] - v;
  if (t < nn) off[n0 + t] = e0 + excl;
  if (b == gridDim.x - 1 && t == 0) off[NN] = e1;   // == NE
  cnt_s[t] = excl;                 // becomes scatter cursor
  __syncthreads();
  if (n <= CSR_CAP) {
    for (int i = t; i < n; i += 512) {
      int2 p = ebuf[e0 + i];
      int loc = atomicAdd(&cnt_s[p.y - n0], 1);
      lnbr[loc] = p.x << 7;        // pre-scaled by D
    }
    __syncthreads();
    for (int i = t; i < n; i += 512) nbr[e0 + i] = lnbr[i];   // coalesced
  } else {                         // safety fallback (never expected)
    for (int i = t; i < n; i += 512) {
      int2 p = ebuf[e0 + i];
      int loc = atomicAdd(&cnt_s[p.y - n0], 1);
      nbr[e0 + loc] = p.x << 7;
    }
  }
}

// ---- segmented mean: one wave per node; 4 edge-groups x 16 lanes x 16B -----
// nbr[] holds pre-scaled src*D element offsets.
__global__ __launch_bounds__(256) void agg_k(
    const ushort* __restrict__ X, const int* __restrict__ nbr,
    const int* __restrict__ off, ushort* __restrict__ mean) {
  const int wave = threadIdx.x >> 6, lane = threadIdx.x & 63;
  const int node = blockIdx.x * 4 + wave;
  if (node >= NN) return;
  const int j0 = off[node], j1 = off[node + 1];
  const int g = lane >> 4, l15 = lane & 15;
  float a[8];
  #pragma unroll
  for (int k = 0; k < 8; ++k) a[k] = 0.f;
  int j = j0 + g;
  for (; j + 4 < j1; j += 8) {     // 2 edges per group in flight
    int s0 = nbr[j], s1 = nbr[j + 4];
    uint4 v0 = *(const uint4*)(X + (size_t)(unsigned)s0 + l15 * 8);
    uint4 v1 = *(const uint4*)(X + (size_t)(unsigned)s1 + l15 * 8);
    unsigned int w0[4] = {v0.x, v0.y, v0.z, v0.w};
    unsigned int w1[4] = {v1.x, v1.y, v1.z, v1.w};
    #pragma unroll
    for (int k = 0; k < 4; ++k) {
      union { unsigned int u; float f; } lo0, hi0, lo1, hi1;
      lo0.u = w0[k] << 16; hi0.u = w0[k] & 0xffff0000u;
      lo1.u = w1[k] << 16; hi1.u = w1[k] & 0xffff0000u;
      a[2 * k]     += lo0.f + lo1.f;
      a[2 * k + 1] += hi0.f + hi1.f;
    }
  }
  if (j < j1) {
    uint4 v0 = *(const uint4*)(X + (size_t)(unsigned)nbr[j] + l15 * 8);
    unsigned int w0[4] = {v0.x, v0.y, v0.z, v0.w};
    #pragma unroll
    for (int k = 0; k < 4; ++k) {
      union { unsigned int u; float f; } lo0, hi0;
      lo0.u = w0[k] << 16; hi0.u = w0[k] & 0xffff0000u;
      a[2 * k]     += lo0.f;
      a[2 * k + 1] += hi0.f;
    }
  }
  #pragma unroll
  for (int k = 0; k < 8; ++k) {    // reduce the 4 edge-groups
    a[k] += __shfl_xor(a[k], 16, 64);
    a[k] += __shfl_xor(a[k], 32, 64);
  }
  if (g == 0) {
    int deg = j1 - j0;
    float inv = 1.f / (float)(deg > 1 ? deg : 1);
    uint4 o;
    o.x = (unsigned int)f2bf(a[0] * inv) | ((unsigned int)f2bf(a[1] * inv) << 16);
    o.y = (unsigned int)f2bf(a[2] * inv) | ((unsigned int)f2bf(a[3] * inv) << 16);
    o.z = (unsigned int)f2bf(a[4] * inv) | ((unsigned int)f2bf(a[5] * inv) << 16);
    o.w = (unsigned int)f2bf(a[6] * inv) | ((unsigned int)f2bf(a[7] * inv) << 16);
    *(uint4*)(mean + (size_t)node * D + l15 * 8) = o;
  }
}

// ============================================================================
// Fused SAGE layer: Y = relu([X, relu(mean@Wl^T + X@Wr^T + bl)] @ Wc^T + bc)
// h via wave-private LDS. ROUND-10: reverted to round-8 exact structure
// (round-9 prefetch pipeline WORSENED the spill: WRITE 60MB, MfmaUtil 7%).
// NEW: when P != nullptr (layer 1), the x2 output packs are written to the
// now-dead hlds rows instead of HBM, and the output projection
// P[node,0:32] = x2[node]@Wo^T (gemm_po's verified pattern) runs in-place.
// Deletes gemm_po dispatch + 25.6MB x2 write + 25.6MB x2 re-read.
// ============================================================================
#define STAGE_WH(Wp, ldwv, HALF)                                               \
  __syncthreads();                                                             \
  _Pragma("unroll")                                                            \
  for (int it = 0; it < 4; ++it) {                                             \
    int combo = it * 4 + wave;                                                 \
    int cc = combo >> 2, kk = combo & 3;                                       \
    *(uint4*)(&wlds[(combo * 64 + lane) * 8]) =                                \
        *(const uint4*)((Wp) + (size_t)(((HALF) * 4 + cc) * 16 + l15) * (ldwv) + kk * 32 + q * 8); \
  }                                                                            \
  __syncthreads();

#define MFMA_HALF(bfr, HALF)                                                   \
  _Pragma("unroll")                                                            \
  for (int ks = 0; ks < 4; ++ks)                                               \
    _Pragma("unroll")                                                          \
    for (int cl = 0; cl < 4; ++cl) {                                           \
      short8 bf = *(const short8*)(&wlds[((cl * 4 + ks) * 64 + lane) * 8]);    \
      acc[0][(HALF) * 4 + cl] =                                                \
          __builtin_amdgcn_mfma_f32_16x16x32_bf16(bf, (bfr)[0][ks], acc[0][(HALF) * 4 + cl], 0, 0, 0); \
      acc[1][(HALF) * 4 + cl] =                                                \
          __builtin_amdgcn_mfma_f32_16x16x32_bf16(bf, (bfr)[1][ks], acc[1][(HALF) * 4 + cl], 0, 0, 0); \
    }

#define MFMA_HHALF(HALF)                                                       \
  _Pragma("unroll")                                                            \
  for (int ks = 0; ks < 4; ++ks) {                                             \
    short8 h0 = *(const short8*)(&hlds[hb0 + ks * 32 + q * 8]);                \
    short8 h1 = *(const short8*)(&hlds[hb1 + ks * 32 + q * 8]);                \
    _Pragma("unroll")                                                          \
    for (int cl = 0; cl < 4; ++cl) {                                           \
      short8 bf = *(const short8*)(&wlds[((cl * 4 + ks) * 64 + lane) * 8]);    \
      acc[0][(HALF) * 4 + cl] =                                                \
          __builtin_amdgcn_mfma_f32_16x16x32_bf16(bf, h0, acc[0][(HALF) * 4 + cl], 0, 0, 0); \
      acc[1][(HALF) * 4 + cl] =                                                \
          __builtin_amdgcn_mfma_f32_16x16x32_bf16(bf, h1, acc[1][(HALF) * 4 + cl], 0, 0, 0); \
    }                                                                          \
  }

#define HLDW 132   // ushorts per h row (264B): b128 reads 2 lanes/bank (free)

__global__ __launch_bounds__(256, 2) void fused_layer_k(
    const ushort* __restrict__ MEAN, const ushort* __restrict__ X,
    const ushort* __restrict__ Wl, const ushort* __restrict__ Wr,
    const ushort* __restrict__ Wc,   // [128][256] row-major
    const ushort* __restrict__ Wo,   // [16][256] row-major (used iff P)
    const ushort* __restrict__ bl, const ushort* __restrict__ bc,
    ushort* __restrict__ Y, float* __restrict__ P, int nrows)
{
  __shared__ ushort wlds[16 * 64 * 8];     // 16 KiB W half-stage
  __shared__ ushort hlds[128 * HLDW];      // 33 KiB h (wave-private 32-row slices)
  const int tid = threadIdx.x;
  const int wave = tid >> 6, lane = tid & 63;
  const int l15 = lane & 15, q = lane >> 4;
  const int nb = blockIdx.x * 128 + wave * 32;   // this wave's 32 node rows

  int r0 = nb + l15;      if (r0 > nrows - 1) r0 = nrows - 1;  // clamp (stores guarded)
  int r1 = nb + 16 + l15; if (r1 > nrows - 1) r1 = nrows - 1;

  // node B-fragments (lane16 = node, q*8 contiguous k)
  short8 am[2][4], ax[2][4];
  #pragma unroll
  for (int ks = 0; ks < 4; ++ks) {
    am[0][ks] = *(const short8*)(MEAN + (size_t)r0 * D + ks * 32 + q * 8);
    am[1][ks] = *(const short8*)(MEAN + (size_t)r1 * D + ks * 32 + q * 8);
    ax[0][ks] = *(const short8*)(X    + (size_t)r0 * D + ks * 32 + q * 8);
    ax[1][ks] = *(const short8*)(X    + (size_t)r1 * D + ks * 32 + q * 8);
  }

  f32x4 acc[2][8];
  #pragma unroll
  for (int rt = 0; rt < 2; ++rt)
    #pragma unroll
    for (int c = 0; c < 8; ++c) acc[rt][c] = (f32x4){0.f, 0.f, 0.f, 0.f};

  // ---- GEMM1: h = relu(mean@Wl^T + X@Wr^T + bl) ----------------------------
  STAGE_WH(Wl, D, 0);  MFMA_HALF(am, 0);
  STAGE_WH(Wl, D, 1);  MFMA_HALF(am, 1);
  STAGE_WH(Wr, D, 0);  MFMA_HALF(ax, 0);
  STAGE_WH(Wr, D, 1);  MFMA_HALF(ax, 1);

  // epilogue1: bias+relu, write h packs to wave-private LDS (no barrier:
  // this wave alone writes/reads rows nb..nb+31)
  #pragma unroll
  for (int c = 0; c < 8; ++c) {
    ushort4 bv = *(const ushort4*)(bl + c * 16 + q * 4);
    #pragma unroll
    for (int rt = 0; rt < 2; ++rt) {
      float v0 = acc[rt][c][0] + bf2f(bv.x); v0 = v0 > 0.f ? v0 : 0.f;
      float v1 = acc[rt][c][1] + bf2f(bv.y); v1 = v1 > 0.f ? v1 : 0.f;
      float v2 = acc[rt][c][2] + bf2f(bv.z); v2 = v2 > 0.f ? v2 : 0.f;
      float v3 = acc[rt][c][3] + bf2f(bv.w); v3 = v3 > 0.f ? v3 : 0.f;
      uint2 o;
      o.x = (unsigned int)f2bf(v0) | ((unsigned int)f2bf(v1) << 16);
      o.y = (unsigned int)f2bf(v2) | ((unsigned int)f2bf(v3) << 16);
      int nl = wave * 32 + rt * 16 + l15;          // local row this lane produced
      *(uint2*)(&hlds[nl * HLDW + c * 16 + q * 4]) = o;
    }
  }

  // ---- GEMM2: Y = relu(X@Wc[:, :128]^T + h@Wc[:, 128:]^T + bc) -------------
  #pragma unroll
  for (int rt = 0; rt < 2; ++rt)
    #pragma unroll
    for (int c = 0; c < 8; ++c) acc[rt][c] = (f32x4){0.f, 0.f, 0.f, 0.f};

  const int hb0 = (wave * 32 + l15) * HLDW;        // h B-frag row for rt=0
  const int hb1 = (wave * 32 + 16 + l15) * HLDW;   // h B-frag row for rt=1

  STAGE_WH(Wc, 2 * D, 0);      MFMA_HALF(ax, 0);
  STAGE_WH(Wc, 2 * D, 1);      MFMA_HALF(ax, 1);
  STAGE_WH(Wc + D, 2 * D, 0);  MFMA_HHALF(0);
  STAGE_WH(Wc + D, 2 * D, 1);  MFMA_HHALF(1);

  // epilogue2: bias+relu. P==null: packed 8B stores of Y. P!=null: x2 packs
  // go to the (now dead) hlds rows; x2 never touches HBM.
  const bool doP = (P != nullptr);
  #pragma unroll
  for (int c = 0; c < 8; ++c) {
    ushort4 bv = *(const ushort4*)(bc + c * 16 + q * 4);
    #pragma unroll
    for (int rt = 0; rt < 2; ++rt) {
      int node = nb + rt * 16 + l15;
      float v0 = acc[rt][c][0] + bf2f(bv.x); v0 = v0 > 0.f ? v0 : 0.f;
      float v1 = acc[rt][c][1] + bf2f(bv.y); v1 = v1 > 0.f ? v1 : 0.f;
      float v2 = acc[rt][c][2] + bf2f(bv.z); v2 = v2 > 0.f ? v2 : 0.f;
      float v3 = acc[rt][c][3] + bf2f(bv.w); v3 = v3 > 0.f ? v3 : 0.f;
      uint2 o;
      o.x = (unsigned int)f2bf(v0) | ((unsigned int)f2bf(v1) << 16);
      o.y = (unsigned int)f2bf(v2) | ((unsigned int)f2bf(v3) << 16);
      if (doP) {
        int nl = wave * 32 + rt * 16 + l15;
        *(uint2*)(&hlds[nl * HLDW + c * 16 + q * 4]) = o;
      } else if (node < nrows) {
        *(uint2*)(Y + (size_t)node * D + c * 16 + q * 4) = o;
      }
    }
  }

  // ---- fused output projection: P[node,0:32] = x2[node] @ Wo^T -------------
  // (gemm_po's verified pattern; x2 B-fragments read from wave-private hlds)
  if (doP) {
    #pragma unroll
    for (int rt = 0; rt < 2; ++rt) {
      f32x4 ap0 = (f32x4){0.f, 0.f, 0.f, 0.f};
      f32x4 ap1 = (f32x4){0.f, 0.f, 0.f, 0.f};
      const int hb = (wave * 32 + rt * 16 + l15) * HLDW;
      #pragma unroll
      for (int ks = 0; ks < 4; ++ks) {
        short8 af = *(const short8*)(&hlds[hb + ks * 32 + q * 8]);
        short8 b0 = *(const short8*)(Wo + (size_t)l15 * 256 + ks * 32 + q * 8);
        short8 b1 = *(const short8*)(Wo + (size_t)l15 * 256 + 128 + ks * 32 + q * 8);
        ap0 = __builtin_amdgcn_mfma_f32_16x16x32_bf16(af, b0, ap0, 0, 0, 0);
        ap1 = __builtin_amdgcn_mfma_f32_16x16x32_bf16(af, b1, ap1, 0, 0, 0);
      }
      #pragma unroll
      for (int r = 0; r < 4; ++r) {
        int node = nb + rt * 16 + q * 4 + r;
        if (node < nrows) {
          P[(size_t)node * 32 + l15]      = ap0[r];
          P[(size_t)node * 32 + 16 + l15] = ap1[r];
        }
      }
    }
  }
}

// ---- out[e,c] = P[src[e]][c] + P[dst[e]][16+c] + bo[c] ---------------------
__global__ __launch_bounds__(256) void edge_sum_k(
    const float* __restrict__ P, const int* __restrict__ src, const int* __restrict__ dst,
    const ushort* __restrict__ bo, const int* __restrict__ flags,
    void* __restrict__ outv, int E)
{
  int gid = blockIdx.x * blockDim.x + threadIdx.x;
  if (gid >= E * 4) return;
  int e = gid >> 2, cq = (gid & 3) * 4;
  int s = src[e], d = dst[e];
  float4 a = *(const float4*)(P + (size_t)s * 32 + cq);
  float4 b = *(const float4*)(P + (size_t)d * 32 + 16 + cq);
  float4 o;
  o.x = a.x + b.x + bf2f(bo[cq + 0]);
  o.y = a.y + b.y + bf2f(bo[cq + 1]);
  o.z = a.z + b.z + bf2f(bo[cq + 2]);
  o.w = a.w + b.w + bf2f(bo[cq + 3]);
  if (flags[0]) {
    ((float4*)outv)[gid] = o;
  } else {
    ushort4 u;
    u.x = f2bf(o.x); u.y = f2bf(o.y); u.z = f2bf(o.z); u.w = f2bf(o.w);
    ((ushort4*)outv)[gid] = u;
  }
}

extern "C" void kernel_launch(void* const* d_in, const int* in_sizes, int n_in,
                              void* d_out, int out_size, void* d_ws, size_t ws_size,
                              hipStream_t stream) {
  const void* x_in = d_in[0];
  const int*  ei   = (const int*)d_in[1];

  // workspace layout (bytes): total ~64.6 MB
  char* ws = (char*)d_ws;
  int*    idx   = (int*)(ws + 0);              //  8,000,000 (src | dst)
  int*    bhist = (int*)(ws + 8000000);        //        784 (NBKT)
  int*    flags = (int*)(ws + 8400000);        //        256
  ushort* wb    = (ushort*)(ws + 8400256);     //    205,600
  int*    off   = (int*)(ws + 8605856);        //    400,004
  int*    bstart= (int*)(ws + 9005872);        //        788 (NBKT+1)
  int*    nbr   = (int*)(ws + 9405872);        //  4,000,000
  int*    bcur  = (int*)(ws + 13405872);       //        784
  ushort* buf1  = (ushort*)(ws + 13407440);    // 25,600,000 (ebuf -> x1)
  ushort* buf2  = (ushort*)(ws + 39007440);    // 25,600,000 (xb; later P 12.8MB)
  ushort* dscr  = (ushort*)d_out;              // d_out scratch: meanL0 / meanL1
  int2*   ebuf  = (int2*)buf1;                 // alias: dead before fused L0
  float*  P     = (float*)buf2;                // alias: buf2 (x) dead after L0

  int* src = idx;
  int* dst = idx + NE;

  ushort* Wl0 = wb + 0,      *Wr0 = wb + 16384, *Wl1 = wb + 32768, *Wr1 = wb + 49152;
  ushort* Wc  = wb + 65536,  *Wo  = wb + 98304;
  ushort* bl0 = wb + 102400, *bl1 = wb + 102528, *bc = wb + 102656, *bo = wb + 102784;

  WPtrs w;
  w.p[0] = d_in[2];  w.p[1] = d_in[4];  w.p[2] = d_in[5];  w.p[3] = d_in[7];
  w.p[4] = d_in[8];  w.p[5] = d_in[10]; w.p[6] = d_in[3];  w.p[7] = d_in[6];
  w.p[8] = d_in[9];  w.p[9] = d_in[11];

  const int gblocks = (NN + 127) / 128;        // 782
  const int n4 = NN * D / 4;
  const int agrid = (NN + 3) / 4;              // 25,000 (4 nodes/block)

  sniff_k<<<1, 256, 0, stream>>>((const ushort*)x_in, (const unsigned int*)ei, flags, bhist);
  convert_idx_k<<<256, 256, 0, stream>>>(ei, flags, idx, bhist);
  convert_x_k<<<(n4 + 255) / 256, 256, 0, stream>>>(x_in, flags, buf2);

  // ---- build CSR via two-level multisplit (scanb fused with convert_w) -----
  scan_convw_k<<<1 + (WTOT + 255) / 256, 256, 0, stream>>>(bhist, bstart, bcur, w, flags, wb);
  msplit_k<<<MS_NBLK, 512, 0, stream>>>(src, dst, bcur, ebuf);
  csr_k<<<NBKT, 512, 0, stream>>>(ebuf, bstart, off, nbr);

  // ---- layer 0: x=buf2 -> mean=dscr -> x1=buf1 (h stays on-chip) -----------
  agg_k<<<agrid, 256, 0, stream>>>(buf2, nbr, off, dscr);
  fused_layer_k<<<gblocks, 256, 0, stream>>>(dscr, buf2, Wl0, Wr0, Wc, Wo, bl0, bc,
                                             buf1, nullptr, NN);

  // ---- layer 1: x1=buf1 -> mean=dscr -> P=buf2 (x2 + P fused on-chip) ------
  agg_k<<<agrid, 256, 0, stream>>>(buf1, nbr, off, dscr);
  fused_layer_k<<<gblocks, 256, 0, stream>>>(dscr, buf1, Wl1, Wr1, Wc, Wo, bl1, bc,
                                             nullptr, P, NN);

  // ---- edge classifier: gather-sum over factored P -------------------------
  edge_sum_k<<<(4 * NE + 255) / 256, 256, 0, stream>>>(P, src, dst, bo, flags, d_out, NE);
}

// Round 11
// 403.713 us; speedup vs baseline: 1.1549x; 1.0334x over previous
//
#include <hip/hip_runtime.h>
#include <hip/hip_bf16.h>

#define NN 100000      // nodes
#define NE 1000000     // edges
#define D  128         // hidden / input dim
#define NC 16          // classes

typedef short short8 __attribute__((ext_vector_type(8)));
typedef float f32x4  __attribute__((ext_vector_type(4)));

__device__ __forceinline__ float bf2f(ushort u) {
  union { unsigned int i; float f; } v; v.i = ((unsigned int)u) << 16; return v.f;
}
__device__ __forceinline__ ushort f2bf(float f) {
  union { float f; unsigned int i; } v; v.f = f;
  unsigned int x = v.i;
  return (ushort)((x + 0x7FFFu + ((x >> 16) & 1u)) >> 16);  // RNE
}

#define BSH 9
#define NBKT ((NN + 511) >> BSH)                 // 196
#define MS_NBLK 256
#define MS_EPB ((NE + MS_NBLK - 1) / MS_NBLK)    // 3907
#define CSR_CAP 8192

// ---- sniff dtypes + zero bucket histogram ----------------------------------
__global__ void sniff_k(const ushort* __restrict__ xr, const unsigned int* __restrict__ ei,
                        int* __restrict__ flags, int* __restrict__ bhist) {
  int t = threadIdx.x;
  if (t < NBKT) bhist[t] = 0;
  if (t != 0 || blockIdx.x != 0) return;
  int f32 = 0;
  for (int i = 0; i < 128; ++i) {
    unsigned int e = ((unsigned int)xr[i] >> 7) & 0xFFu;
    if (e < 97u || e > 157u) f32 = 1;
  }
  flags[0] = f32;
  unsigned int s = 0;
  for (int i = 1; i < 256; i += 2) s |= ei[i];   // int64 < 2^31 => hi words all 0
  flags[1] = (s == 0) ? 1 : 0;
}

// ---- indices + fused dst bucket histogram, grid-stride 256 blocks ----------
__global__ __launch_bounds__(256) void convert_idx_k(
    const int* __restrict__ ei, const int* __restrict__ flags,
    int* __restrict__ idx, int* __restrict__ bhist) {
  __shared__ int h[NBKT];
  for (int t = threadIdx.x; t < NBKT; t += 256) h[t] = 0;
  __syncthreads();
  const int stride = 256 * 256;
  const int i64 = flags[1];
  for (int i = blockIdx.x * 256 + threadIdx.x; i < 2 * NE; i += stride) {
    int v = i64 ? ei[2 * i] : ei[i];   // int64: take low word
    v = v < 0 ? 0 : (v >= NN ? NN - 1 : v);
    idx[i] = v;
    if (i >= NE) atomicAdd(&h[v >> BSH], 1);   // dst half feeds histogram
  }
  __syncthreads();
  for (int t = threadIdx.x; t < NBKT; t += 256) if (h[t]) atomicAdd(&bhist[t], h[t]);
}

// ---- convert x to canonical bf16 -------------------------------------------
__global__ void convert_x_k(const void* __restrict__ xin, const int* __restrict__ flags,
                            ushort* __restrict__ xb) {
  int i = blockIdx.x * blockDim.x + threadIdx.x;
  const int n4 = NN * D / 4;
  if (i >= n4) return;
  ushort4 o;
  if (flags[0]) {
    float4 v = ((const float4*)xin)[i];
    o.x = f2bf(v.x); o.y = f2bf(v.y); o.z = f2bf(v.z); o.w = f2bf(v.w);
  } else {
    o = ((const ushort4*)xin)[i];
  }
  ((ushort4*)xb)[i] = o;
}

// ---- bucket scan (block 0) + weight conversion (blocks 1..) ----------------
struct WPtrs { const void* p[10]; };
#define WTOT 102800
__global__ __launch_bounds__(256) void scan_convw_k(
    const int* __restrict__ bhist, int* __restrict__ bstart, int* __restrict__ bcur,
    WPtrs w, const int* __restrict__ flags, ushort* __restrict__ wb) {
  if (blockIdx.x == 0) {
    __shared__ int tmp[256];
    const int t = threadIdx.x;
    int v = (t < NBKT) ? bhist[t] : 0;
    tmp[t] = v;
    __syncthreads();
    for (int s = 1; s < 256; s <<= 1) {
      int u = (t >= s) ? tmp[t - s] : 0;
      __syncthreads();
      tmp[t] += u;
      __syncthreads();
    }
    if (t < NBKT) {
      int ex = tmp[t] - v;
      bstart[t] = ex;
      bcur[t] = ex;
    }
    if (t == NBKT - 1) bstart[NBKT] = tmp[t];
  } else {
    const int off[10] = {0, 16384, 32768, 49152, 65536, 98304, 102400, 102528, 102656, 102784};
    int i = (blockIdx.x - 1) * 256 + threadIdx.x;
    if (i >= WTOT) return;
    int seg = 0;
    #pragma unroll
    for (int s2 = 1; s2 < 10; ++s2) if (i >= off[s2]) seg = s2;
    int j = i - off[seg];
    wb[i] = flags[0] ? f2bf(((const float*)w.p[seg])[j]) : ((const ushort*)w.p[seg])[j];
  }
}

__global__ __launch_bounds__(512) void msplit_k(const int* __restrict__ src,
                                                const int* __restrict__ dst,
                                                int* __restrict__ bcur,
                                                int2* __restrict__ ebuf) {
  __shared__ int2 ep[MS_EPB];        // ~31.3 KiB
  __shared__ int hist[NBKT];
  __shared__ int gbase[NBKT];
  const int e0 = blockIdx.x * MS_EPB;
  int n = NE - e0; if (n > MS_EPB) n = MS_EPB;
  for (int t = threadIdx.x; t < NBKT; t += 512) hist[t] = 0;
  __syncthreads();
  for (int t = threadIdx.x; t < n; t += 512) {
    int s = src[e0 + t], d = dst[e0 + t];
    ep[t] = make_int2(s, d);
    atomicAdd(&hist[d >> BSH], 1);
  }
  __syncthreads();
  for (int t = threadIdx.x; t < NBKT; t += 512) {
    gbase[t] = atomicAdd(&bcur[t], hist[t]);   // one chunk per (block,bucket)
    hist[t] = 0;                               // reuse as local cursor
  }
  __syncthreads();
  for (int t = threadIdx.x; t < n; t += 512) {
    int2 p = ep[t];
    int b = p.y >> BSH;
    int loc = atomicAdd(&hist[b], 1);
    ebuf[gbase[b] + loc] = p;                  // contiguous within chunk
  }
}

// nbr[] stores src*128 (pre-scaled element offset) — agg_k saves a mul/widen
__global__ __launch_bounds__(512) void csr_k(const int2* __restrict__ ebuf,
                                             const int* __restrict__ bstart,
                                             int* __restrict__ off,
                                             int* __restrict__ nbr) {
  __shared__ int cnt_s[512];
  __shared__ int ofs_s[512];
  __shared__ int lnbr[CSR_CAP];      // 32 KiB staging
  const int b = blockIdx.x;
  const int n0 = b << BSH;
  int nn = NN - n0; if (nn > 512) nn = 512;
  const int e0 = bstart[b], e1 = bstart[b + 1];
  const int n = e1 - e0;
  const int t = threadIdx.x;
  cnt_s[t] = 0;
  __syncthreads();
  for (int i = t; i < n; i += 512)
    atomicAdd(&cnt_s[ebuf[e0 + i].y - n0], 1);
  __syncthreads();
  int v = cnt_s[t];
  ofs_s[t] = v;
  __syncthreads();
  for (int s = 1; s < 512; s <<= 1) {          // inclusive Hillis-Steele
    int u = (t >= s) ? ofs_s[t - s] : 0;
    __syncthreads();
    ofs_s[t] += u;
    __syncthreads();
  }
  const int excl = ofs_s[t] - v;
  if (t < nn) off[n0 + t] = e0 + excl;
  if (b == gridDim.x - 1 && t == 0) off[NN] = e1;   // == NE
  cnt_s[t] = excl;                 // becomes scatter cursor
  __syncthreads();
  if (n <= CSR_CAP) {
    for (int i = t; i < n; i += 512) {
      int2 p = ebuf[e0 + i];
      int loc = atomicAdd(&cnt_s[p.y - n0], 1);
      lnbr[loc] = p.x << 7;        // pre-scaled by D
    }
    __syncthreads();
    for (int i = t; i < n; i += 512) nbr[e0 + i] = lnbr[i];   // coalesced
  } else {                         // safety fallback (never expected)
    for (int i = t; i < n; i += 512) {
      int2 p = ebuf[e0 + i];
      int loc = atomicAdd(&cnt_s[p.y - n0], 1);
      nbr[e0 + loc] = p.x << 7;
    }
  }
}

// ---- segmented mean: one wave per node; 4 edge-groups x 16 lanes x 16B -----
// nbr[] holds pre-scaled src*D element offsets.
__global__ __launch_bounds__(256) void agg_k(
    const ushort* __restrict__ X, const int* __restrict__ nbr,
    const int* __restrict__ off, ushort* __restrict__ mean) {
  const int wave = threadIdx.x >> 6, lane = threadIdx.x & 63;
  const int node = blockIdx.x * 4 + wave;
  if (node >= NN) return;
  const int j0 = off[node], j1 = off[node + 1];
  const int g = lane >> 4, l15 = lane & 15;
  float a[8];
  #pragma unroll
  for (int k = 0; k < 8; ++k) a[k] = 0.f;
  int j = j0 + g;
  for (; j + 4 < j1; j += 8) {     // 2 edges per group in flight
    int s0 = nbr[j], s1 = nbr[j + 4];
    uint4 v0 = *(const uint4*)(X + (size_t)(unsigned)s0 + l15 * 8);
    uint4 v1 = *(const uint4*)(X + (size_t)(unsigned)s1 + l15 * 8);
    unsigned int w0[4] = {v0.x, v0.y, v0.z, v0.w};
    unsigned int w1[4] = {v1.x, v1.y, v1.z, v1.w};
    #pragma unroll
    for (int k = 0; k < 4; ++k) {
      union { unsigned int u; float f; } lo0, hi0, lo1, hi1;
      lo0.u = w0[k] << 16; hi0.u = w0[k] & 0xffff0000u;
      lo1.u = w1[k] << 16; hi1.u = w1[k] & 0xffff0000u;
      a[2 * k]     += lo0.f + lo1.f;
      a[2 * k + 1] += hi0.f + hi1.f;
    }
  }
  if (j < j1) {
    uint4 v0 = *(const uint4*)(X + (size_t)(unsigned)nbr[j] + l15 * 8);
    unsigned int w0[4] = {v0.x, v0.y, v0.z, v0.w};
    #pragma unroll
    for (int k = 0; k < 4; ++k) {
      union { unsigned int u; float f; } lo0, hi0;
      lo0.u = w0[k] << 16; hi0.u = w0[k] & 0xffff0000u;
      a[2 * k]     += lo0.f;
      a[2 * k + 1] += hi0.f;
    }
  }
  #pragma unroll
  for (int k = 0; k < 8; ++k) {    // reduce the 4 edge-groups
    a[k] += __shfl_xor(a[k], 16, 64);
    a[k] += __shfl_xor(a[k], 32, 64);
  }
  if (g == 0) {
    int deg = j1 - j0;
    float inv = 1.f / (float)(deg > 1 ? deg : 1);
    uint4 o;
    o.x = (unsigned int)f2bf(a[0] * inv) | ((unsigned int)f2bf(a[1] * inv) << 16);
    o.y = (unsigned int)f2bf(a[2] * inv) | ((unsigned int)f2bf(a[3] * inv) << 16);
    o.z = (unsigned int)f2bf(a[4] * inv) | ((unsigned int)f2bf(a[5] * inv) << 16);
    o.w = (unsigned int)f2bf(a[6] * inv) | ((unsigned int)f2bf(a[7] * inv) << 16);
    *(uint4*)(mean + (size_t)node * D + l15 * 8) = o;
  }
}

// ============================================================================
// Fused SAGE layer: Y = relu([X, relu(mean@Wl^T + X@Wr^T + bl)] @ Wc^T + bc)
// + optional fused output projection P = x2@Wo^T (layer 1).
// ROUND-11: 8 waves x 16 rows per 512-thread block (was 4 waves x 32 rows).
// Grid stays 782 blocks; LDS unchanged (16KB wlds + 33KB hlds = 49KB -> 3
// blocks/CU); per-wave registers halve (acc 32 + am/ax 32) -> clear of the
// 84-VGPR spill cliff that haunted rounds 5/6/9; waves/CU 12 -> 16-24 for
// latency hiding of the 8 serialized W-stage barriers.
// h and x2 routed through wave-private hlds rows (rows wave*16..wave*16+15,
// no barrier needed for them).
// ============================================================================
#define STAGE_WH(Wp, ldwv, HALF)                                               \
  __syncthreads();                                                             \
  _Pragma("unroll")                                                            \
  for (int it = 0; it < 2; ++it) {                                             \
    int combo = it * 8 + wave;                                                 \
    int cc = combo >> 2, kk = combo & 3;                                       \
    *(uint4*)(&wlds[(combo * 64 + lane) * 8]) =                                \
        *(const uint4*)((Wp) + (size_t)(((HALF) * 4 + cc) * 16 + l15) * (ldwv) + kk * 32 + q * 8); \
  }                                                                            \
  __syncthreads();

#define MFMA_HALF(bfr, HALF)                                                   \
  _Pragma("unroll")                                                            \
  for (int ks = 0; ks < 4; ++ks)                                               \
    _Pragma("unroll")                                                          \
    for (int cl = 0; cl < 4; ++cl) {                                           \
      short8 bf = *(const short8*)(&wlds[((cl * 4 + ks) * 64 + lane) * 8]);    \
      acc[(HALF) * 4 + cl] =                                                   \
          __builtin_amdgcn_mfma_f32_16x16x32_bf16(bf, (bfr)[ks], acc[(HALF) * 4 + cl], 0, 0, 0); \
    }

#define MFMA_HHALF(HALF)                                                       \
  _Pragma("unroll")                                                            \
  for (int ks = 0; ks < 4; ++ks) {                                             \
    short8 h0 = *(const short8*)(&hlds[hb0 + ks * 32 + q * 8]);                \
    _Pragma("unroll")                                                          \
    for (int cl = 0; cl < 4; ++cl) {                                           \
      short8 bf = *(const short8*)(&wlds[((cl * 4 + ks) * 64 + lane) * 8]);    \
      acc[(HALF) * 4 + cl] =                                                   \
          __builtin_amdgcn_mfma_f32_16x16x32_bf16(bf, h0, acc[(HALF) * 4 + cl], 0, 0, 0); \
    }                                                                          \
  }

#define HLDW 132   // ushorts per h row (264B): b128 reads 2 lanes/bank (free)

__global__ __launch_bounds__(512, 2) void fused_layer_k(
    const ushort* __restrict__ MEAN, const ushort* __restrict__ X,
    const ushort* __restrict__ Wl, const ushort* __restrict__ Wr,
    const ushort* __restrict__ Wc,   // [128][256] row-major
    const ushort* __restrict__ Wo,   // [16][256] row-major (used iff P)
    const ushort* __restrict__ bl, const ushort* __restrict__ bc,
    ushort* __restrict__ Y, float* __restrict__ P, int nrows)
{
  __shared__ ushort wlds[16 * 64 * 8];     // 16 KiB W half-stage
  __shared__ ushort hlds[128 * HLDW];      // 33 KiB h/x2 (wave-private 16-row slices)
  const int tid = threadIdx.x;
  const int wave = tid >> 6, lane = tid & 63;
  const int l15 = lane & 15, q = lane >> 4;
  const int nb = blockIdx.x * 128 + wave * 16;   // this wave's 16 node rows

  int r0 = nb + l15; if (r0 > nrows - 1) r0 = nrows - 1;  // clamp (stores guarded)

  // node B-fragments (lane16 = node, q*8 contiguous k)
  short8 am[4], ax[4];
  #pragma unroll
  for (int ks = 0; ks < 4; ++ks) {
    am[ks] = *(const short8*)(MEAN + (size_t)r0 * D + ks * 32 + q * 8);
    ax[ks] = *(const short8*)(X    + (size_t)r0 * D + ks * 32 + q * 8);
  }

  f32x4 acc[8];
  #pragma unroll
  for (int c = 0; c < 8; ++c) acc[c] = (f32x4){0.f, 0.f, 0.f, 0.f};

  // ---- GEMM1: h = relu(mean@Wl^T + X@Wr^T + bl) ----------------------------
  STAGE_WH(Wl, D, 0);  MFMA_HALF(am, 0);
  STAGE_WH(Wl, D, 1);  MFMA_HALF(am, 1);
  STAGE_WH(Wr, D, 0);  MFMA_HALF(ax, 0);
  STAGE_WH(Wr, D, 1);  MFMA_HALF(ax, 1);

  // epilogue1: bias+relu, write h packs to wave-private LDS rows
  // (C layout: node col = l15, h-col = c*16 + q*4 + r  [m89-verified])
  #pragma unroll
  for (int c = 0; c < 8; ++c) {
    ushort4 bv = *(const ushort4*)(bl + c * 16 + q * 4);
    float v0 = acc[c][0] + bf2f(bv.x); v0 = v0 > 0.f ? v0 : 0.f;
    float v1 = acc[c][1] + bf2f(bv.y); v1 = v1 > 0.f ? v1 : 0.f;
    float v2 = acc[c][2] + bf2f(bv.z); v2 = v2 > 0.f ? v2 : 0.f;
    float v3 = acc[c][3] + bf2f(bv.w); v3 = v3 > 0.f ? v3 : 0.f;
    uint2 o;
    o.x = (unsigned int)f2bf(v0) | ((unsigned int)f2bf(v1) << 16);
    o.y = (unsigned int)f2bf(v2) | ((unsigned int)f2bf(v3) << 16);
    int nl = wave * 16 + l15;          // local row this lane produced
    *(uint2*)(&hlds[nl * HLDW + c * 16 + q * 4]) = o;
  }

  // ---- GEMM2: Y = relu(X@Wc[:, :128]^T + h@Wc[:, 128:]^T + bc) -------------
  #pragma unroll
  for (int c = 0; c < 8; ++c) acc[c] = (f32x4){0.f, 0.f, 0.f, 0.f};

  const int hb0 = (wave * 16 + l15) * HLDW;        // h B-frag row

  STAGE_WH(Wc, 2 * D, 0);      MFMA_HALF(ax, 0);
  STAGE_WH(Wc, 2 * D, 1);      MFMA_HALF(ax, 1);
  STAGE_WH(Wc + D, 2 * D, 0);  MFMA_HHALF(0);
  STAGE_WH(Wc + D, 2 * D, 1);  MFMA_HHALF(1);

  // epilogue2: bias+relu. P==null: packed 8B stores of Y. P!=null: x2 packs
  // go to the (now dead) hlds rows; x2 never touches HBM.
  const bool doP = (P != nullptr);
  #pragma unroll
  for (int c = 0; c < 8; ++c) {
    ushort4 bv = *(const ushort4*)(bc + c * 16 + q * 4);
    int node = nb + l15;
    float v0 = acc[c][0] + bf2f(bv.x); v0 = v0 > 0.f ? v0 : 0.f;
    float v1 = acc[c][1] + bf2f(bv.y); v1 = v1 > 0.f ? v1 : 0.f;
    float v2 = acc[c][2] + bf2f(bv.z); v2 = v2 > 0.f ? v2 : 0.f;
    float v3 = acc[c][3] + bf2f(bv.w); v3 = v3 > 0.f ? v3 : 0.f;
    uint2 o;
    o.x = (unsigned int)f2bf(v0) | ((unsigned int)f2bf(v1) << 16);
    o.y = (unsigned int)f2bf(v2) | ((unsigned int)f2bf(v3) << 16);
    if (doP) {
      int nl = wave * 16 + l15;
      *(uint2*)(&hlds[nl * HLDW + c * 16 + q * 4]) = o;
    } else if (node < nrows) {
      *(uint2*)(Y + (size_t)node * D + c * 16 + q * 4) = o;
    }
  }

  // ---- fused output projection: P[node,0:32] = x2[node] @ Wo^T -------------
  // (gemm_po's verified pattern; x2 B-fragments read from wave-private hlds)
  if (doP) {
    f32x4 ap0 = (f32x4){0.f, 0.f, 0.f, 0.f};
    f32x4 ap1 = (f32x4){0.f, 0.f, 0.f, 0.f};
    const int hb = (wave * 16 + l15) * HLDW;
    #pragma unroll
    for (int ks = 0; ks < 4; ++ks) {
      short8 af = *(const short8*)(&hlds[hb + ks * 32 + q * 8]);
      short8 b0 = *(const short8*)(Wo + (size_t)l15 * 256 + ks * 32 + q * 8);
      short8 b1 = *(const short8*)(Wo + (size_t)l15 * 256 + 128 + ks * 32 + q * 8);
      ap0 = __builtin_amdgcn_mfma_f32_16x16x32_bf16(af, b0, ap0, 0, 0, 0);
      ap1 = __builtin_amdgcn_mfma_f32_16x16x32_bf16(af, b1, ap1, 0, 0, 0);
    }
    #pragma unroll
    for (int r = 0; r < 4; ++r) {
      int node = nb + q * 4 + r;
      if (node < nrows) {
        P[(size_t)node * 32 + l15]      = ap0[r];
        P[(size_t)node * 32 + 16 + l15] = ap1[r];
      }
    }
  }
}

// ---- out[e,c] = P[src[e]][c] + P[dst[e]][16+c] + bo[c] ---------------------
__global__ __launch_bounds__(256) void edge_sum_k(
    const float* __restrict__ P, const int* __restrict__ src, const int* __restrict__ dst,
    const ushort* __restrict__ bo, const int* __restrict__ flags,
    void* __restrict__ outv, int E)
{
  int gid = blockIdx.x * blockDim.x + threadIdx.x;
  if (gid >= E * 4) return;
  int e = gid >> 2, cq = (gid & 3) * 4;
  int s = src[e], d = dst[e];
  float4 a = *(const float4*)(P + (size_t)s * 32 + cq);
  float4 b = *(const float4*)(P + (size_t)d * 32 + 16 + cq);
  float4 o;
  o.x = a.x + b.x + bf2f(bo[cq + 0]);
  o.y = a.y + b.y + bf2f(bo[cq + 1]);
  o.z = a.z + b.z + bf2f(bo[cq + 2]);
  o.w = a.w + b.w + bf2f(bo[cq + 3]);
  if (flags[0]) {
    ((float4*)outv)[gid] = o;
  } else {
    ushort4 u;
    u.x = f2bf(o.x); u.y = f2bf(o.y); u.z = f2bf(o.z); u.w = f2bf(o.w);
    ((ushort4*)outv)[gid] = u;
  }
}

extern "C" void kernel_launch(void* const* d_in, const int* in_sizes, int n_in,
                              void* d_out, int out_size, void* d_ws, size_t ws_size,
                              hipStream_t stream) {
  const void* x_in = d_in[0];
  const int*  ei   = (const int*)d_in[1];

  // workspace layout (bytes): total ~64.6 MB
  char* ws = (char*)d_ws;
  int*    idx   = (int*)(ws + 0);              //  8,000,000 (src | dst)
  int*    bhist = (int*)(ws + 8000000);        //        784 (NBKT)
  int*    flags = (int*)(ws + 8400000);        //        256
  ushort* wb    = (ushort*)(ws + 8400256);     //    205,600
  int*    off   = (int*)(ws + 8605856);        //    400,004
  int*    bstart= (int*)(ws + 9005872);        //        788 (NBKT+1)
  int*    nbr   = (int*)(ws + 9405872);        //  4,000,000
  int*    bcur  = (int*)(ws + 13405872);       //        784
  ushort* buf1  = (ushort*)(ws + 13407440);    // 25,600,000 (ebuf -> x1)
  ushort* buf2  = (ushort*)(ws + 39007440);    // 25,600,000 (xb; later P 12.8MB)
  ushort* dscr  = (ushort*)d_out;              // d_out scratch: meanL0 / meanL1
  int2*   ebuf  = (int2*)buf1;                 // alias: dead before fused L0
  float*  P     = (float*)buf2;                // alias: buf2 (x) dead after L0

  int* src = idx;
  int* dst = idx + NE;

  ushort* Wl0 = wb + 0,      *Wr0 = wb + 16384, *Wl1 = wb + 32768, *Wr1 = wb + 49152;
  ushort* Wc  = wb + 65536,  *Wo  = wb + 98304;
  ushort* bl0 = wb + 102400, *bl1 = wb + 102528, *bc = wb + 102656, *bo = wb + 102784;

  WPtrs w;
  w.p[0] = d_in[2];  w.p[1] = d_in[4];  w.p[2] = d_in[5];  w.p[3] = d_in[7];
  w.p[4] = d_in[8];  w.p[5] = d_in[10]; w.p[6] = d_in[3];  w.p[7] = d_in[6];
  w.p[8] = d_in[9];  w.p[9] = d_in[11];

  const int gblocks = (NN + 127) / 128;        // 782
  const int n4 = NN * D / 4;
  const int agrid = (NN + 3) / 4;              // 25,000 (4 nodes/block)

  sniff_k<<<1, 256, 0, stream>>>((const ushort*)x_in, (const unsigned int*)ei, flags, bhist);
  convert_idx_k<<<256, 256, 0, stream>>>(ei, flags, idx, bhist);
  convert_x_k<<<(n4 + 255) / 256, 256, 0, stream>>>(x_in, flags, buf2);

  // ---- build CSR via two-level multisplit (scanb fused with convert_w) -----
  scan_convw_k<<<1 + (WTOT + 255) / 256, 256, 0, stream>>>(bhist, bstart, bcur, w, flags, wb);
  msplit_k<<<MS_NBLK, 512, 0, stream>>>(src, dst, bcur, ebuf);
  csr_k<<<NBKT, 512, 0, stream>>>(ebuf, bstart, off, nbr);

  // ---- layer 0: x=buf2 -> mean=dscr -> x1=buf1 (h stays on-chip) -----------
  agg_k<<<agrid, 256, 0, stream>>>(buf2, nbr, off, dscr);
  fused_layer_k<<<gblocks, 512, 0, stream>>>(dscr, buf2, Wl0, Wr0, Wc, Wo, bl0, bc,
                                             buf1, nullptr, NN);

  // ---- layer 1: x1=buf1 -> mean=dscr -> P=buf2 (x2 + P fused on-chip) ------
  agg_k<<<agrid, 256, 0, stream>>>(buf1, nbr, off, dscr);
  fused_layer_k<<<gblocks, 512, 0, stream>>>(dscr, buf1, Wl1, Wr1, Wc, Wo, bl1, bc,
                                             nullptr, P, NN);

  // ---- edge classifier: gather-sum over factored P -------------------------
  edge_sum_k<<<(4 * NE + 255) / 256, 256, 0, stream>>>(P, src, dst, bo, flags, d_out, NE);
}